// Round 3
// baseline (328.489 us; speedup 1.0000x reference)
//
#include <hip/hip_runtime.h>

#define NWIN 49
#define DIM  128
#define NH   4
#define HD   32
#define SCALE 0.17677669529663687f

using short8 = __attribute__((ext_vector_type(8))) short;
using us4    = __attribute__((ext_vector_type(4))) unsigned short;
using f32x4  = __attribute__((ext_vector_type(4))) float;

union Frag { uint4 u; short8 s; };

static __device__ __forceinline__ short8 ld8p(const void* p) {
    Frag fr; fr.u = *(const uint4*)p; return fr.s;
}
static __device__ __forceinline__ unsigned short f2bf(float f) {
    union { float f; unsigned i; } v; v.f = f;
    unsigned r = v.i + 0x7fffu + ((v.i >> 16) & 1u);   // RNE
    return (unsigned short)(r >> 16);
}

// DPP cross-lane (VALU, not LDS-pipe). Reduction over the 16-lane row:
// xor1 = quad_perm[1,0,3,2]=0xB1, xor2 = quad_perm[2,3,0,1]=0x4E,
// then row_ror:4 (0x124) and row_ror:8 (0x128) — circulant steps that
// complete the all-reduce across the 4 quads of the 16-lane row.
template <int CTRL>
static __device__ __forceinline__ float dppf(float x) {
    int v = __float_as_int(x);
    v = __builtin_amdgcn_update_dpp(v, v, CTRL, 0xF, 0xF, false);
    return __int_as_float(v);
}
static __device__ __forceinline__ float rowmax16(float m) {
    m = fmaxf(m, dppf<0xB1>(m));
    m = fmaxf(m, dppf<0x4E>(m));
    m = fmaxf(m, dppf<0x124>(m));
    m = fmaxf(m, dppf<0x128>(m));
    return m;
}
static __device__ __forceinline__ float rowsum16(float s) {
    s += dppf<0xB1>(s);
    s += dppf<0x4E>(s);
    s += dppf<0x124>(s);
    s += dppf<0x128>(s);
    return s;
}

// ---- prep: bf16 transposed weights + precombined bias+mask table ----
__global__ __launch_bounds__(256) void prep_kernel(
    const float* __restrict__ qkv_w,    // [128,384]
    const float* __restrict__ proj_w,   // [128,128]
    const float* __restrict__ mask,     // [64,49,49]
    const float* __restrict__ bias_tab, // [169,4]
    const int*   __restrict__ rel_index,// [49,49]
    unsigned short* __restrict__ wqkvT, // [384,128] bf16
    unsigned short* __restrict__ projT, // [128,128] bf16
    float*          __restrict__ BM)    // [64,4,49,49] fp32: mask+bias
{
    int tid = blockIdx.x * 256 + threadIdx.x;
    if (tid < 49152) {
        int n = tid >> 7, k = tid & 127;
        wqkvT[tid] = f2bf(qkv_w[k * 384 + n]);
    } else if (tid < 65536) {
        int t2 = tid - 49152;
        int n = t2 >> 7, k = t2 & 127;
        projT[t2] = f2bf(proj_w[k * 128 + n]);
    } else if (tid < 65536 + 64 * NH * 2401) {
        int idx = tid - 65536;
        int wh = idx / 2401, ij = idx % 2401;
        int wm = wh >> 2, h = wh & 3;
        BM[idx] = mask[wm * 2401 + ij] + bias_tab[rel_index[ij] * NH + h];
    }
}

// LDS layout (bytes), all arrays XOR-swizzled: local_off ^= ((row&7)<<4).
//   [0, 12544)  XS [49][128] bf16 (row stride 256 B)  -- aliased by OS
//   [12544 + h*10368)  per-head pool:
//      +0     QH [49][32] bf16 (3136 B, row stride 64 B) } aliased by
//      +3136  KH [49][32] bf16 (3136 B)                  } PS [49][64] (6272 B)
//      +6272  VT [32][64] bf16 (4096 B, d-stride 128 B)
// Total 54016 B -> 3 blocks/CU (24 waves/CU, 6/SIMD).
// All fragment reads of pad rows (49..63) are CLAMPED to row 48 (LDS
// broadcast): padded S rows are discarded, padded S cols overwritten by
// -1e30 mask, padded V k-slots multiply exact-zero P -- semantics intact.
#define SWZ(r)  (((r) & 7) << 4)
#define HP_B   12544
#define HP_SZ  10368
#define KH_B   3136
#define VT_B   6272
#define LDS_SZ 54016

__global__ __launch_bounds__(512) void winattn_kernel(
    const float* __restrict__ x,        // [4096,49,128]
    const float* __restrict__ qkv_b,    // [384]
    const float* __restrict__ proj_b,   // [128]
    const unsigned short* __restrict__ wqkvT,  // [384,128] bf16
    const unsigned short* __restrict__ projT,  // [128,128] bf16
    const float* __restrict__ BM,       // [64,4,49,49]
    float*       __restrict__ out)      // [4096,49,128]
{
    __shared__ __align__(16) char pool[LDS_SZ];

    const int b = blockIdx.x;
    const int t = threadIdx.x;
    const int w = t >> 6;        // wave 0..7
    const int lane = t & 63;
    const int q = lane >> 4;     // quad 0..3
    const int l16 = lane & 15;
    const int wm = b & 63;

    // ---- stage X -> bf16 LDS XS[49][128] (swizzled) ----
    for (int c = t; c < NWIN * 16; c += 512) {
        const int row = c >> 4, g = c & 15;
        const float4* src = (const float4*)(x + (size_t)b * (NWIN * DIM) + row * DIM + g * 8);
        float4 f0 = src[0], f1 = src[1];
        uint4 p;
        p.x = (unsigned)f2bf(f0.x) | ((unsigned)f2bf(f0.y) << 16);
        p.y = (unsigned)f2bf(f0.z) | ((unsigned)f2bf(f0.w) << 16);
        p.z = (unsigned)f2bf(f1.x) | ((unsigned)f2bf(f1.y) << 16);
        p.w = (unsigned)f2bf(f1.z) | ((unsigned)f2bf(f1.w) << 16);
        *(uint4*)(pool + ((row * 256 + g * 16) ^ SWZ(row))) = p;
    }
    __syncthreads();   // sync #1

    // ---- phase B: QKV. Wave w -> head (w&3), mt in {w>>2, (w>>2)+2} ----
    {
        const int hb = w & 3;
        const int mt0 = w >> 2;
        char* hp = pool + HP_B + hb * HP_SZ;

        short8 af[2][4];
        #pragma unroll
        for (int mti = 0; mti < 2; ++mti) {
            const int mt = mt0 + 2 * mti;
            int rr = mt * 16 + l16;
            if (mt == 3) rr = rr > 48 ? 48 : rr;   // clamp pad rows
            #pragma unroll
            for (int ks = 0; ks < 4; ++ks)
                af[mti][ks] = ld8p(pool + ((rr * 256 + ks * 64 + q * 16) ^ SWZ(rr)));
        }
        #pragma unroll
        for (int sn = 0; sn < 6; ++sn) {
            const int s = sn >> 1, nn = sn & 1;
            const int colbase = s * 128 + hb * 32 + nn * 16;
            short8 bfr[4];
            #pragma unroll
            for (int ks = 0; ks < 4; ++ks)
                bfr[ks] = ld8p(wqkvT + (size_t)(colbase + l16) * 128 + ks * 32 + q * 8);
            const float bias = qkv_b[colbase + l16];
            const int cl = nn * 16 + l16;
            #pragma unroll
            for (int mti = 0; mti < 2; ++mti) {
                const int mt = mt0 + 2 * mti;
                f32x4 acc = {0.f, 0.f, 0.f, 0.f};
                #pragma unroll
                for (int ks = 0; ks < 4; ++ks)
                    acc = __builtin_amdgcn_mfma_f32_16x16x32_bf16(af[mti][ks], bfr[ks], acc, 0, 0, 0);
                if (s == 2) {
                    // V^T: 4 acc values = 4 consecutive k-slots -> one 8B store
                    us4 pk;
                    #pragma unroll
                    for (int r = 0; r < 4; ++r) pk[r] = f2bf(acc[r] + bias);
                    *(us4*)(hp + VT_B + ((cl * 128 + mt * 32 + q * 8) ^ SWZ(cl))) = pk;
                } else {
                    #pragma unroll
                    for (int r = 0; r < 4; ++r) {
                        const int row = mt * 16 + q * 4 + r;
                        if (row < NWIN) {
                            const float val = acc[r] + bias;
                            if (s == 0)
                                *(unsigned short*)(hp + ((row * 64 + cl * 2) ^ SWZ(row))) = f2bf(val * SCALE);
                            else
                                *(unsigned short*)(hp + KH_B + ((row * 64 + cl * 2) ^ SWZ(row))) = f2bf(val);
                        }
                    }
                }
            }
        }
    }
    __syncthreads();   // sync #2: QKV complete; XS free -> OS may alias it

    // ---- phase C: wave w -> head (w>>1), mt-half (w&1) ----
    const int h = w >> 1, mh = w & 1;
    char* hp = pool + HP_B + h * HP_SZ;

    float sv[2][4][4];  // [mti][nt][r]
    {
        short8 kf[4];
        #pragma unroll
        for (int nt = 0; nt < 4; ++nt) {
            int rn = nt * 16 + l16;
            if (nt == 3) rn = rn > 48 ? 48 : rn;
            kf[nt] = ld8p(hp + KH_B + ((rn * 64 + q * 16) ^ SWZ(rn)));
        }
        #pragma unroll
        for (int mti = 0; mti < 2; ++mti) {
            const int mt = 2 * mh + mti;
            int rr = mt * 16 + l16;
            if (mt == 3) rr = rr > 48 ? 48 : rr;
            short8 a = ld8p(hp + ((rr * 64 + q * 16) ^ SWZ(rr)));
            #pragma unroll
            for (int nt = 0; nt < 4; ++nt) {
                f32x4 acc = {0.f, 0.f, 0.f, 0.f};
                acc = __builtin_amdgcn_mfma_f32_16x16x32_bf16(a, kf[nt], acc, 0, 0, 0);
                #pragma unroll
                for (int r = 0; r < 4; ++r) sv[mti][nt][r] = acc[r];
            }
        }
    }
    // add combined bias+mask; pad cols -> -inf  (registers only)
    {
        const float* bm = BM + (size_t)(wm * NH + h) * 2401;
        #pragma unroll
        for (int mti = 0; mti < 2; ++mti)
            #pragma unroll
            for (int r = 0; r < 4; ++r) {
                const int i = (2 * mh + mti) * 16 + q * 4 + r;
                const float* bmr = bm + i * 49;
                #pragma unroll
                for (int nt = 0; nt < 4; ++nt) {
                    const int j = nt * 16 + l16;
                    if (j >= NWIN)      sv[mti][nt][r] = -1e30f;
                    else if (i < NWIN)  sv[mti][nt][r] += bmr[j];
                    // i>=49: garbage, confined to never-stored rows
                }
            }
    }
    // softmax per row, fully in registers; cross-lane via DPP (VALU)
    #pragma unroll
    for (int mti = 0; mti < 2; ++mti)
        #pragma unroll
        for (int r = 0; r < 4; ++r) {
            float m = fmaxf(fmaxf(sv[mti][0][r], sv[mti][1][r]),
                            fmaxf(sv[mti][2][r], sv[mti][3][r]));
            m = rowmax16(m);
            float sum = 0.f;
            #pragma unroll
            for (int nt = 0; nt < 4; ++nt) {
                float e = __expf(sv[mti][nt][r] - m);
                sv[mti][nt][r] = e;
                sum += e;
            }
            sum = rowsum16(sum);
            const float rs = 1.f / sum;
            #pragma unroll
            for (int nt = 0; nt < 4; ++nt) sv[mti][nt][r] *= rs;
        }

    // Both waves sharing this head pool must finish their S-MFMA reads of
    // QH/KH before PS (which aliases them) is written.
    __syncthreads();   // sync #2b

    // P -> LDS PS[49][64] (own 32-row half only)
    #pragma unroll
    for (int mti = 0; mti < 2; ++mti)
        #pragma unroll
        for (int r = 0; r < 4; ++r) {
            const int i = (2 * mh + mti) * 16 + q * 4 + r;
            if (i < NWIN) {
                #pragma unroll
                for (int nt = 0; nt < 4; ++nt)
                    *(unsigned short*)(hp + ((i * 128 + (nt * 16 + l16) * 2) ^ SWZ(i))) = f2bf(sv[mti][nt][r]);
            }
        }

    // ---- phase D: O_h = P V (own rows; PS rows are self-written) ----
    #pragma unroll
    for (int nt2 = 0; nt2 < 2; ++nt2) {
        const int d = nt2 * 16 + l16;
        short8 bv0 = ld8p(hp + VT_B + ((d * 128 + q * 16) ^ SWZ(d)));
        short8 bv1 = ld8p(hp + VT_B + ((d * 128 + 64 + q * 16) ^ SWZ(d)));
        #pragma unroll
        for (int mti = 0; mti < 2; ++mti) {
            const int mt = 2 * mh + mti;
            int rr = mt * 16 + l16;
            if (mt == 3) rr = rr > 48 ? 48 : rr;
            f32x4 acc = {0.f, 0.f, 0.f, 0.f};
            acc = __builtin_amdgcn_mfma_f32_16x16x32_bf16(
                ld8p(hp + ((rr * 128 + q * 16) ^ SWZ(rr))), bv0, acc, 0, 0, 0);
            acc = __builtin_amdgcn_mfma_f32_16x16x32_bf16(
                ld8p(hp + ((rr * 128 + 64 + q * 16) ^ SWZ(rr))), bv1, acc, 0, 0, 0);
            #pragma unroll
            for (int r = 0; r < 4; ++r) {
                const int row = mt * 16 + q * 4 + r;
                if (row < NWIN)
                    *(unsigned short*)(pool + ((row * 256 + (h * 32 + nt2 * 16 + l16) * 2) ^ SWZ(row))) = f2bf(acc[r]);  // OS
            }
        }
    }
    __syncthreads();   // sync #3: full O assembled

    // ---- phase E: out = O @ proj_w + proj_b. Wave w -> col-tile nt=w ----
    {
        const int nt = w;
        short8 bfr[4];
        #pragma unroll
        for (int ks = 0; ks < 4; ++ks)
            bfr[ks] = ld8p(projT + (size_t)(nt * 16 + l16) * 128 + ks * 32 + q * 8);
        const int col = nt * 16 + l16;
        const float pb = proj_b[col];
        #pragma unroll
        for (int mt = 0; mt < 4; ++mt) {
            int rr = mt * 16 + l16;
            if (mt == 3) rr = rr > 48 ? 48 : rr;
            f32x4 acc = {0.f, 0.f, 0.f, 0.f};
            #pragma unroll
            for (int ks = 0; ks < 4; ++ks)
                acc = __builtin_amdgcn_mfma_f32_16x16x32_bf16(
                    ld8p(pool + ((rr * 256 + ks * 64 + q * 16) ^ SWZ(rr))), bfr[ks], acc, 0, 0, 0);
            #pragma unroll
            for (int r = 0; r < 4; ++r) {
                const int row = mt * 16 + q * 4 + r;
                if (row < NWIN)
                    out[(size_t)b * (NWIN * DIM) + row * 128 + col] = acc[r] + pb;
            }
        }
    }
}

extern "C" void kernel_launch(void* const* d_in, const int* in_sizes, int n_in,
                              void* d_out, int out_size, void* d_ws, size_t ws_size,
                              hipStream_t stream) {
    const int B = in_sizes[0] / (NWIN * DIM);  // 4096 windows
    unsigned short* wqkvT = (unsigned short*)d_ws;                   //    98304 B
    unsigned short* projT = (unsigned short*)((char*)d_ws + 98304);  //    32768 B
    float*          BM    = (float*)((char*)d_ws + 131072);          //  2458624 B

    prep_kernel<<<2657, 256, 0, stream>>>(
        (const float*)d_in[2],  // qkv_w
        (const float*)d_in[4],  // proj_w
        (const float*)d_in[1],  // mask
        (const float*)d_in[6],  // rel_bias_table
        (const int*)d_in[7],    // rel_index
        wqkvT, projT, BM);

    winattn_kernel<<<B, 512, 0, stream>>>(
        (const float*)d_in[0],  // x
        (const float*)d_in[3],  // qkv_b
        (const float*)d_in[5],  // proj_b
        wqkvT, projT, BM,
        (float*)d_out);
}

// Round 5
// 322.006 us; speedup vs baseline: 1.0201x; 1.0201x over previous
//
#include <hip/hip_runtime.h>

#define NWIN 49
#define DIM  128
#define NH   4
#define HD   32
#define SCALE 0.17677669529663687f

using short8 = __attribute__((ext_vector_type(8))) short;
using us4    = __attribute__((ext_vector_type(4))) unsigned short;
using f32x4  = __attribute__((ext_vector_type(4))) float;

union Frag { uint4 u; short8 s; };

static __device__ __forceinline__ short8 ld8p(const void* p) {
    Frag fr; fr.u = *(const uint4*)p; return fr.s;
}
// RNE bf16 bits land in [31:16]
static __device__ __forceinline__ unsigned rne16(float f) {
    union { float f; unsigned i; } v; v.f = f;
    return v.i + 0x7fffu + ((v.i >> 16) & 1u);
}
static __device__ __forceinline__ unsigned short f2bf(float f) {
    return (unsigned short)(rne16(f) >> 16);
}
// pack bf16(lo) | bf16(hi)<<16 via v_perm_b32 (builtin, no asm):
// combined = {S0=hi', S1=lo'}; sel bytes [2,3,6,7] pick hi16 of each.
static __device__ __forceinline__ unsigned pkbf(float lo, float hi) {
    return __builtin_amdgcn_perm(rne16(hi), rne16(lo), 0x07060302u);
}

// DPP cross-lane (VALU, not LDS-pipe) reduction over the 16-lane row.
template <int CTRL>
static __device__ __forceinline__ float dppf(float x) {
    int v = __float_as_int(x);
    v = __builtin_amdgcn_update_dpp(v, v, CTRL, 0xF, 0xF, false);
    return __int_as_float(v);
}
static __device__ __forceinline__ float rowmax16(float m) {
    m = fmaxf(m, dppf<0xB1>(m));
    m = fmaxf(m, dppf<0x4E>(m));
    m = fmaxf(m, dppf<0x124>(m));
    m = fmaxf(m, dppf<0x128>(m));
    return m;
}
static __device__ __forceinline__ float rowsum16(float s) {
    s += dppf<0xB1>(s);
    s += dppf<0x4E>(s);
    s += dppf<0x124>(s);
    s += dppf<0x128>(s);
    return s;
}

// ---- prep: bf16 transposed weights (Q-part pre-scaled) + bias+mask ----
__global__ __launch_bounds__(256) void prep_kernel(
    const float* __restrict__ qkv_w,    // [128,384]
    const float* __restrict__ proj_w,   // [128,128]
    const float* __restrict__ mask,     // [64,49,49]
    const float* __restrict__ bias_tab, // [169,4]
    const int*   __restrict__ rel_index,// [49,49]
    unsigned short* __restrict__ wqkvT, // [384,128] bf16, rows<128 scaled
    unsigned short* __restrict__ projT, // [128,128] bf16
    float*          __restrict__ BM)    // [64,4,49,49] fp32: mask+bias
{
    int tid = blockIdx.x * 256 + threadIdx.x;
    if (tid < 49152) {
        int n = tid >> 7, k = tid & 127;
        float v = qkv_w[k * 384 + n];
        if (n < 128) v *= SCALE;        // fold softmax scale into Q weights
        wqkvT[tid] = f2bf(v);
    } else if (tid < 65536) {
        int t2 = tid - 49152;
        int n = t2 >> 7, k = t2 & 127;
        projT[t2] = f2bf(proj_w[k * 128 + n]);
    } else if (tid < 65536 + 64 * NH * 2401) {
        int idx = tid - 65536;
        int wh = idx / 2401, ij = idx % 2401;
        int wm = wh >> 2, h = wh & 3;
        BM[idx] = mask[wm * 2401 + ij] + bias_tab[rel_index[ij] * NH + h];
    }
}

// LDS layout (bytes), all arrays XOR-swizzled: local_off ^= ((row&7)<<4).
//   [0, 12544)  XS [49][128] bf16 (row stride 256 B)  -- aliased by OS
//   [12544 + h*10368)  per-head pool:
//      +0     QH [49][32] bf16 (3136 B, row stride 64 B) } aliased by
//      +3136  KH [49][32] bf16 (3136 B)                  } PS [49][64] (6272 B)
//      +6272  VT [32][64] bf16 (4096 B, d-stride 128 B)
// Total 54016 B -> 3 blocks/CU. Pad-row fragment reads clamp to row 48.
#define SWZ(r)  (((r) & 7) << 4)
#define HP_B   12544
#define HP_SZ  10368
#define KH_B   3136
#define VT_B   6272
#define LDS_SZ 54016

__global__ __launch_bounds__(512) void winattn_kernel(
    const float* __restrict__ x,        // [4096,49,128]
    const float* __restrict__ qkv_b,    // [384]
    const float* __restrict__ proj_b,   // [128]
    const unsigned short* __restrict__ wqkvT,  // [384,128] bf16 (Q scaled)
    const unsigned short* __restrict__ projT,  // [128,128] bf16
    const float* __restrict__ BM,       // [64,4,49,49]
    float*       __restrict__ out)      // [4096,49,128]
{
    __shared__ __align__(16) char pool[LDS_SZ];

    const int b = blockIdx.x;
    const int t = threadIdx.x;
    const int w = t >> 6;        // wave 0..7
    const int lane = t & 63;
    const int q = lane >> 4;     // quad 0..3
    const int l16 = lane & 15;
    const int wm = b & 63;

    // ---- stage X -> bf16 LDS XS[49][128] (swizzled), perm-packed ----
    for (int c = t; c < NWIN * 16; c += 512) {
        const int row = c >> 4, g = c & 15;
        const float4* src = (const float4*)(x + (size_t)b * (NWIN * DIM) + row * DIM + g * 8);
        float4 f0 = src[0], f1 = src[1];
        uint4 p;
        p.x = pkbf(f0.x, f0.y); p.y = pkbf(f0.z, f0.w);
        p.z = pkbf(f1.x, f1.y); p.w = pkbf(f1.z, f1.w);
        *(uint4*)(pool + ((row * 256 + g * 16) ^ SWZ(row))) = p;
    }
    __syncthreads();   // sync #1

    // ---- phase B: QKV. Wave w -> head (w&3), mt in {w>>2, (w>>2)+2} ----
    {
        const int hb = w & 3;
        const int mt0 = w >> 2;
        char* hp = pool + HP_B + hb * HP_SZ;

        short8 af[2][4];
        #pragma unroll
        for (int mti = 0; mti < 2; ++mti) {
            const int mt = mt0 + 2 * mti;
            int rr = mt * 16 + l16;
            if (mt == 3) rr = rr > 48 ? 48 : rr;   // clamp pad rows
            #pragma unroll
            for (int ks = 0; ks < 4; ++ks)
                af[mti][ks] = ld8p(pool + ((rr * 256 + ks * 64 + q * 16) ^ SWZ(rr)));
        }
        #pragma unroll
        for (int sn = 0; sn < 6; ++sn) {
            const int s = sn >> 1, nn = sn & 1;
            const int colbase = s * 128 + hb * 32 + nn * 16;
            short8 bfr[4];
            #pragma unroll
            for (int ks = 0; ks < 4; ++ks)
                bfr[ks] = ld8p(wqkvT + (size_t)(colbase + l16) * 128 + ks * 32 + q * 8);
            float bias = qkv_b[colbase + l16];
            if (s == 0) bias *= SCALE;             // weights pre-scaled too
            const int cl = nn * 16 + l16;
            #pragma unroll
            for (int mti = 0; mti < 2; ++mti) {
                const int mt = mt0 + 2 * mti;
                f32x4 acc = {bias, bias, bias, bias};   // bias in C-init
                #pragma unroll
                for (int ks = 0; ks < 4; ++ks)
                    acc = __builtin_amdgcn_mfma_f32_16x16x32_bf16(af[mti][ks], bfr[ks], acc, 0, 0, 0);
                const unsigned u01 = pkbf(acc[0], acc[1]);
                const unsigned u23 = pkbf(acc[2], acc[3]);
                if (s == 2) {
                    // V^T: 4 acc values = 4 consecutive k-slots -> one 8B store
                    union { unsigned u[2]; us4 v; } pk;
                    pk.u[0] = u01; pk.u[1] = u23;
                    *(us4*)(hp + VT_B + ((cl * 128 + mt * 32 + q * 8) ^ SWZ(cl))) = pk.v;
                } else {
                    char* base = hp + (s == 1 ? KH_B : 0);
                    const int r0 = mt * 16 + q * 4;
                    if (r0 < NWIN)
                        *(unsigned short*)(base + ((r0 * 64 + cl * 2) ^ SWZ(r0))) = (unsigned short)u01;
                    if (r0 + 1 < NWIN)
                        *(unsigned short*)(base + (((r0 + 1) * 64 + cl * 2) ^ SWZ(r0 + 1))) = (unsigned short)(u01 >> 16);
                    if (r0 + 2 < NWIN)
                        *(unsigned short*)(base + (((r0 + 2) * 64 + cl * 2) ^ SWZ(r0 + 2))) = (unsigned short)u23;
                    if (r0 + 3 < NWIN)
                        *(unsigned short*)(base + (((r0 + 3) * 64 + cl * 2) ^ SWZ(r0 + 3))) = (unsigned short)(u23 >> 16);
                }
            }
        }
    }
    __syncthreads();   // sync #2: QKV complete; XS free -> OS may alias it

    // ---- phase C: wave w -> head (w>>1), mt-half (w&1) ----
    const int h = w >> 1, mh = w & 1;
    char* hp = pool + HP_B + h * HP_SZ;

    float sv[2][4][4];  // [mti][nt][r]
    {
        short8 kf[4];
        #pragma unroll
        for (int nt = 0; nt < 4; ++nt) {
            int rn = nt * 16 + l16;
            if (nt == 3) rn = rn > 48 ? 48 : rn;
            kf[nt] = ld8p(hp + KH_B + ((rn * 64 + q * 16) ^ SWZ(rn)));
        }
        #pragma unroll
        for (int mti = 0; mti < 2; ++mti) {
            const int mt = 2 * mh + mti;
            int rr = mt * 16 + l16;
            if (mt == 3) rr = rr > 48 ? 48 : rr;
            short8 a = ld8p(hp + ((rr * 64 + q * 16) ^ SWZ(rr)));
            #pragma unroll
            for (int nt = 0; nt < 4; ++nt) {
                f32x4 acc = {0.f, 0.f, 0.f, 0.f};
                acc = __builtin_amdgcn_mfma_f32_16x16x32_bf16(a, kf[nt], acc, 0, 0, 0);
                #pragma unroll
                for (int r = 0; r < 4; ++r) sv[mti][nt][r] = acc[r];
            }
        }
    }
    // add combined bias+mask; pad cols -> -inf  (registers only)
    {
        const float* bm = BM + (size_t)(wm * NH + h) * 2401;
        #pragma unroll
        for (int mti = 0; mti < 2; ++mti)
            #pragma unroll
            for (int r = 0; r < 4; ++r) {
                const int i = (2 * mh + mti) * 16 + q * 4 + r;
                const float* bmr = bm + i * 49;
                #pragma unroll
                for (int nt = 0; nt < 4; ++nt) {
                    const int j = nt * 16 + l16;
                    if (j >= NWIN)      sv[mti][nt][r] = -1e30f;
                    else if (i < NWIN)  sv[mti][nt][r] += bmr[j];
                    // i>=49: garbage, confined to never-stored rows
                }
            }
    }
    // softmax per row (DPP). P kept UNNORMALIZED; 1/sum deferred to PV.
    float rsv[2][4];
    #pragma unroll
    for (int mti = 0; mti < 2; ++mti)
        #pragma unroll
        for (int r = 0; r < 4; ++r) {
            float m = fmaxf(fmaxf(sv[mti][0][r], sv[mti][1][r]),
                            fmaxf(sv[mti][2][r], sv[mti][3][r]));
            m = rowmax16(m);
            float sum = 0.f;
            #pragma unroll
            for (int nt = 0; nt < 4; ++nt) {
                float e = __expf(sv[mti][nt][r] - m);
                sv[mti][nt][r] = e;
                sum += e;
            }
            sum = rowsum16(sum);
            rsv[mti][r] = 1.f / sum;
        }

    // Both waves sharing this head pool must finish their S-MFMA reads of
    // QH/KH before PS (which aliases them) is written.
    __syncthreads();   // sync #2b

    // P -> LDS PS[49][64] (own 32-row half only), perm-packed pairs
    #pragma unroll
    for (int mti = 0; mti < 2; ++mti)
        #pragma unroll
        for (int r = 0; r < 4; ++r) {
            const int i = (2 * mh + mti) * 16 + q * 4 + r;
            if (i < NWIN) {
                const unsigned u01 = pkbf(sv[mti][0][r], sv[mti][1][r]);
                const unsigned u23 = pkbf(sv[mti][2][r], sv[mti][3][r]);
                *(unsigned short*)(hp + ((i * 128 + l16 * 2) ^ SWZ(i))) = (unsigned short)u01;
                *(unsigned short*)(hp + ((i * 128 + (16 + l16) * 2) ^ SWZ(i))) = (unsigned short)(u01 >> 16);
                *(unsigned short*)(hp + ((i * 128 + (32 + l16) * 2) ^ SWZ(i))) = (unsigned short)u23;
                *(unsigned short*)(hp + ((i * 128 + (48 + l16) * 2) ^ SWZ(i))) = (unsigned short)(u23 >> 16);
            }
        }

    // ---- phase D: O_h = P V; 1/sum applied on the f32 accumulator ----
    #pragma unroll
    for (int nt2 = 0; nt2 < 2; ++nt2) {
        const int d = nt2 * 16 + l16;
        short8 bv0 = ld8p(hp + VT_B + ((d * 128 + q * 16) ^ SWZ(d)));
        short8 bv1 = ld8p(hp + VT_B + ((d * 128 + 64 + q * 16) ^ SWZ(d)));
        #pragma unroll
        for (int mti = 0; mti < 2; ++mti) {
            const int mt = 2 * mh + mti;
            int rr = mt * 16 + l16;
            if (mt == 3) rr = rr > 48 ? 48 : rr;
            f32x4 acc = {0.f, 0.f, 0.f, 0.f};
            acc = __builtin_amdgcn_mfma_f32_16x16x32_bf16(
                ld8p(hp + ((rr * 128 + q * 16) ^ SWZ(rr))), bv0, acc, 0, 0, 0);
            acc = __builtin_amdgcn_mfma_f32_16x16x32_bf16(
                ld8p(hp + ((rr * 128 + 64 + q * 16) ^ SWZ(rr))), bv1, acc, 0, 0, 0);
            const unsigned u01 = pkbf(acc[0] * rsv[mti][0], acc[1] * rsv[mti][1]);
            const unsigned u23 = pkbf(acc[2] * rsv[mti][2], acc[3] * rsv[mti][3]);
            const int r0 = mt * 16 + q * 4;
            const int cb = (h * 32 + nt2 * 16 + l16) * 2;
            if (r0 < NWIN)
                *(unsigned short*)(pool + ((r0 * 256 + cb) ^ SWZ(r0))) = (unsigned short)u01;
            if (r0 + 1 < NWIN)
                *(unsigned short*)(pool + (((r0 + 1) * 256 + cb) ^ SWZ(r0 + 1))) = (unsigned short)(u01 >> 16);
            if (r0 + 2 < NWIN)
                *(unsigned short*)(pool + (((r0 + 2) * 256 + cb) ^ SWZ(r0 + 2))) = (unsigned short)u23;
            if (r0 + 3 < NWIN)
                *(unsigned short*)(pool + (((r0 + 3) * 256 + cb) ^ SWZ(r0 + 3))) = (unsigned short)(u23 >> 16);
        }
    }

    // hoist phase-E global loads above the barrier (latency hides in wait)
    const int ntE = w;
    short8 bfrE[4];
    #pragma unroll
    for (int ks = 0; ks < 4; ++ks)
        bfrE[ks] = ld8p(projT + (size_t)(ntE * 16 + l16) * 128 + ks * 32 + q * 8);
    const int colE = ntE * 16 + l16;
    const float pbE = proj_b[colE];

    __syncthreads();   // sync #3: full O assembled

    // ---- phase E: out = O @ proj_w + proj_b. Wave w -> col-tile nt=w ----
    #pragma unroll
    for (int mt = 0; mt < 4; ++mt) {
        int rr = mt * 16 + l16;
        if (mt == 3) rr = rr > 48 ? 48 : rr;
        f32x4 acc = {0.f, 0.f, 0.f, 0.f};
        #pragma unroll
        for (int ks = 0; ks < 4; ++ks)
            acc = __builtin_amdgcn_mfma_f32_16x16x32_bf16(
                ld8p(pool + ((rr * 256 + ks * 64 + q * 16) ^ SWZ(rr))), bfrE[ks], acc, 0, 0, 0);
        #pragma unroll
        for (int r = 0; r < 4; ++r) {
            const int row = mt * 16 + q * 4 + r;
            if (row < NWIN)
                out[(size_t)b * (NWIN * DIM) + row * 128 + colE] = acc[r] + pbE;
        }
    }
}

extern "C" void kernel_launch(void* const* d_in, const int* in_sizes, int n_in,
                              void* d_out, int out_size, void* d_ws, size_t ws_size,
                              hipStream_t stream) {
    const int B = in_sizes[0] / (NWIN * DIM);  // 4096 windows
    unsigned short* wqkvT = (unsigned short*)d_ws;                   //    98304 B
    unsigned short* projT = (unsigned short*)((char*)d_ws + 98304);  //    32768 B
    float*          BM    = (float*)((char*)d_ws + 131072);          //  2458624 B

    prep_kernel<<<2657, 256, 0, stream>>>(
        (const float*)d_in[2],  // qkv_w
        (const float*)d_in[4],  // proj_w
        (const float*)d_in[1],  // mask
        (const float*)d_in[6],  // rel_bias_table
        (const int*)d_in[7],    // rel_index
        wqkvT, projT, BM);

    winattn_kernel<<<B, 512, 0, stream>>>(
        (const float*)d_in[0],  // x
        (const float*)d_in[3],  // qkv_b
        (const float*)d_in[5],  // proj_b
        wqkvT, projT, BM,
        (float*)d_out);
}